// Round 4
// baseline (60.949 us; speedup 1.0000x reference)
//
#include <hip/hip_runtime.h>

#define NPOS (4*16*64*64)             // 262144 positions
#define KCODES 512
#define CDIM 64
#define OUT_SCALAR_IDX ((size_t)NPOS * CDIM)

// d_ws layout
#define WS_GCOUNT 0                   // 512 * int (used-flags)
#define WS_EMB    4096                // 64 KB: row-major (-2*e) bf16 image, 128 B/row
#define WS_EE     (4096 + 65536)      // 512 * float: ||e||^2 + 1.0 bias

typedef short short8 __attribute__((ext_vector_type(8)));
typedef float f32x4 __attribute__((ext_vector_type(4)));

__device__ __forceinline__ ushort f2bf(float f) {
  uint u = __builtin_bit_cast(uint, f);
  u += 0x7fff + ((u >> 16) & 1);        // RNE
  return (ushort)(u >> 16);
}

// ---- prep: codebook -> -2x bf16 image + biased ee + zero flags ----
__global__ __launch_bounds__(64) void vq_prep(
    const float* __restrict__ emb, char* __restrict__ ws) {
  const int r = blockIdx.x * 64 + threadIdx.x;     // 8 x 64 = 512 rows
  ((int*)(ws + WS_GCOUNT))[r] = 0;
  const float4* er = (const float4*)(emb + r * CDIM);
  char* img = ws + WS_EMB;
  float ee = 0.f;
  #pragma unroll
  for (int q = 0; q < 8; ++q) {
    float4 x = er[2 * q], y = er[2 * q + 1];
    ee = fmaf(x.x, x.x, ee); ee = fmaf(x.y, x.y, ee);
    ee = fmaf(x.z, x.z, ee); ee = fmaf(x.w, x.w, ee);
    ee = fmaf(y.x, y.x, ee); ee = fmaf(y.y, y.y, ee);
    ee = fmaf(y.z, y.z, ee); ee = fmaf(y.w, y.w, ee);
    uint4 ch;
    ch.x = f2bf(-2.f * x.x) | ((uint)f2bf(-2.f * x.y) << 16);
    ch.y = f2bf(-2.f * x.z) | ((uint)f2bf(-2.f * x.w) << 16);
    ch.z = f2bf(-2.f * y.x) | ((uint)f2bf(-2.f * y.y) << 16);
    ch.w = f2bf(-2.f * y.z) | ((uint)f2bf(-2.f * y.w) << 16);
    *(uint4*)(img + r * 128 + q * 16) = ch;
  }
  // bias so distances sit near 1.0 -> fp32 bits monotone as uint
  ((float*)(ws + WS_EE))[r] = ee + 1.0f;
}

__global__ __launch_bounds__(256, 5) void vq_mfma(
    const float* __restrict__ z, const float* __restrict__ emb,
    const char* __restrict__ ws, float* __restrict__ out,
    int* __restrict__ gflags) {
  __shared__ float s_ee[KCODES];      // 2 KB
  __shared__ int s_idx[256];          // 1 KB
  __shared__ int s_hist[KCODES];      // 2 KB

  const int tid = threadIdx.x;
  const int lane = tid & 63;
  const int w = tid >> 6;
  const int col = lane & 15;
  const int kg = lane >> 4;

  // stage biased ee (512 floats) + zero hist
  ((float2*)s_ee)[tid] = ((const float2*)(ws + WS_EE))[tid];
  s_hist[tid] = 0;
  s_hist[tid + 256] = 0;

  // ---- A fragments: 4 row-tiles x 2 K-halves, bf16 ----
  short8 af[4][2];
  const int nb = blockIdx.x * 256 + w * 64;
  #pragma unroll
  for (int rt = 0; rt < 4; ++rt) {
    const int n = nb + rt * 16 + col;
    const int b = n >> 16, sp = n & 65535;
    const float* zp = z + ((size_t)b << 22) + sp;
    #pragma unroll
    for (int h = 0; h < 2; ++h) {
      short8 f;
      #pragma unroll
      for (int j = 0; j < 8; ++j)
        f[j] = (short)f2bf(zp[(size_t)(h * 32 + kg * 8 + j) << 16]);
      af[rt][h] = f;
    }
  }

  __syncthreads();   // s_ee ready

  // ---- hot loop: B streamed from L2-resident global image ----
  uint key[4][4];
  #pragma unroll
  for (int rt = 0; rt < 4; ++rt)
    #pragma unroll
    for (int s = 0; s < 4; ++s) key[rt][s] = 0xFFFFFFFFu;

  const char* img = ws + WS_EMB;
  const int boff = col * 128 + kg * 16;
  short8 b0 = *(const short8*)(img + boff);
  short8 b1 = *(const short8*)(img + boff + 64);
  float eev = s_ee[col];

  #pragma unroll 4
  for (int ct = 0; ct < 32; ++ct) {
    short8 c0 = b0, c1 = b1;
    const float ec = eev;
    const int nct = (ct + 1) & 31;                 // wrap: harmless reload of 0
    b0 = *(const short8*)(img + nct * 2048 + boff);
    b1 = *(const short8*)(img + nct * 2048 + boff + 64);
    eev = s_ee[nct * 16 + col];
    const f32x4 cin = {ec, ec, ec, ec};            // 1 + ||e||^2
    #pragma unroll
    for (int rt = 0; rt < 4; ++rt) {
      f32x4 acc = __builtin_amdgcn_mfma_f32_16x16x32_bf16(af[rt][0], c0, cin, 0, 0, 0);
      acc = __builtin_amdgcn_mfma_f32_16x16x32_bf16(af[rt][1], c1, acc, 0, 0, 0);
      #pragma unroll
      for (int s = 0; s < 4; ++s) {
        // d ~ 1.0 > 0 -> bits monotone; low 5 bits carry ct (first-tile wins ties)
        uint kb = (__builtin_bit_cast(uint, acc[s]) & 0xFFFFFFE0u) | (uint)ct;
        key[rt][s] = kb < key[rt][s] ? kb : key[rt][s];
      }
    }
  }

  // ---- per-row argmin across 16 cols: pure uint-min butterfly ----
  #pragma unroll
  for (int rt = 0; rt < 4; ++rt) {
    #pragma unroll
    for (int s = 0; s < 4; ++s) {
      uint k = (key[rt][s] << 4) | (uint)col;      // (dist, ct, col) lex order
      #pragma unroll
      for (int m = 1; m < 16; m <<= 1) {
        uint o = (uint)__shfl_xor((int)k, m, 64);
        k = o < k ? o : k;
      }
      if (col == 0)
        s_idx[w * 64 + rt * 16 + kg * 4 + s] = (int)(k & 0x1FFu);  // ct*16+col
    }
  }
  __syncthreads();

  // ---- epilogue: exact fp32 emb gather (L2-hot) + coalesced strided write ----
  const int myidx = s_idx[tid];
  atomicAdd(&s_hist[myidx], 1);
  {
    const int n = blockIdx.x * 256 + tid;
    const int b = n >> 16, sp = n & 65535;
    float* op = out + ((size_t)b << 22) + sp;
    const float4* ef = (const float4*)(emb + myidx * CDIM);
    #pragma unroll
    for (int q = 0; q < 16; ++q) {
      float4 e4 = ef[q];
      op[(size_t)(4 * q + 0) << 16] = e4.x;
      op[(size_t)(4 * q + 1) << 16] = e4.y;
      op[(size_t)(4 * q + 2) << 16] = e4.z;
      op[(size_t)(4 * q + 3) << 16] = e4.w;
    }
  }
  __syncthreads();
  // idempotent used-flags (no global atomics; prep re-zeroes each launch)
  if (s_hist[tid]) gflags[tid] = 1;
  if (s_hist[tid + 256]) gflags[tid + 256] = 1;
}

__global__ __launch_bounds__(512) void vq_count(
    const int* __restrict__ gflags, float* __restrict__ out) {
  __shared__ int red[512];
  const int t = threadIdx.x;
  red[t] = (gflags[t] > 0) ? 1 : 0;
  __syncthreads();
  for (int s = 256; s > 0; s >>= 1) {
    if (t < s) red[t] += red[t + s];
    __syncthreads();
  }
  if (t == 0) out[OUT_SCALAR_IDX] = (float)red[0];
}

extern "C" void kernel_launch(void* const* d_in, const int* in_sizes, int n_in,
                              void* d_out, int out_size, void* d_ws, size_t ws_size,
                              hipStream_t stream) {
  const float* z = (const float*)d_in[0];
  const float* emb = (const float*)d_in[1];
  float* out = (float*)d_out;
  char* ws = (char*)d_ws;
  int* gflags = (int*)(ws + WS_GCOUNT);

  vq_prep<<<8, 64, 0, stream>>>(emb, ws);
  vq_mfma<<<NPOS / 256, 256, 0, stream>>>(z, emb, ws, out, gflags);
  vq_count<<<1, 512, 0, stream>>>(gflags, out);
}